// Round 3
// baseline (349.387 us; speedup 1.0000x reference)
//
#include <hip/hip_runtime.h>
#include <stdint.h>

#define P_TOT 2304
#define C_IN  256
#define INTER 128
#define NH    8
#define HD    16

typedef short sh4 __attribute__((ext_vector_type(4)));
typedef short sh8 __attribute__((ext_vector_type(8)));
typedef float fl4 __attribute__((ext_vector_type(4)));

static __device__ __forceinline__ unsigned short f2bf(float f) {
    union { float f; unsigned u; } v; v.f = f;
    return (unsigned short)((v.u + 0x7fffu + ((v.u >> 16) & 1u)) >> 16);
}
static __device__ __forceinline__ float bf2f(unsigned short h) {
    union { unsigned u; float f; } v; v.u = ((unsigned)h) << 16; return v.f;
}

// ---------------- Kernel 0: convert the 4 weight matrices f32 -> bf16 once.
// Wb layout: [Wq 32768][Wk 32768][Wv 32768][Wo 32768]
__global__ __launch_bounds__(256) void k_prep(
    const float* __restrict__ Wq, const float* __restrict__ Wk,
    const float* __restrict__ Wv, const float* __restrict__ Wo,
    unsigned short* __restrict__ Wb) {
    int i = blockIdx.x * 256 + threadIdx.x; // 0..131071
    int seg = i >> 15, off = i & 32767;
    const float* s = (seg == 0 ? Wq : (seg == 1 ? Wk : (seg == 2 ? Wv : Wo)));
    Wb[i] = f2bf(s[off]);
}

// ---------------- Kernel 1: fused transpose + QKV projection.
// grid (36 p-tiles, 12 = pr*4+b). X inputs f32; Q,K transposed [b][p][128] bf16;
// V natural [b][128][p] bf16.
__global__ __launch_bounds__(256) void k_qkv(
    const float* __restrict__ rgb, const float* __restrict__ depth,
    const float* __restrict__ rgbd, const unsigned short* __restrict__ Wb,
    const float* __restrict__ bq, const float* __restrict__ bk,
    const float* __restrict__ bv,
    unsigned short* __restrict__ Qt, unsigned short* __restrict__ Kt,
    unsigned short* __restrict__ Vn) {
    __shared__ __align__(16) unsigned short ldsT[64][264]; // [p_local][channel], +8 pad
    int nt = blockIdx.x, pb = blockIdx.y;
    int pr = pb >> 2, b = pb & 3;
    const unsigned short* W = Wb + pr * 32768;
    const float* bias = (pr == 0 ? bq : (pr == 1 ? bk : bv));
    const float* X = (pr == 0 ? rgb : (pr == 1 ? depth : rgbd)) + (size_t)b * C_IN * P_TOT;
    int tid = threadIdx.x;
    int p0 = nt * 64;
    // Stage transposed tile: ldsT[p][c] = bf16(X[c][p0+p]).
    {
        int pl = (tid & 15) * 4;
        int cb = tid >> 4;
#pragma unroll
        for (int i = 0; i < 16; ++i) {
            int c = i * 16 + cb;
            float4 v = *(const float4*)(X + (size_t)c * P_TOT + p0 + pl);
            ldsT[pl + 0][c] = f2bf(v.x);
            ldsT[pl + 1][c] = f2bf(v.y);
            ldsT[pl + 2][c] = f2bf(v.z);
            ldsT[pl + 3][c] = f2bf(v.w);
        }
    }
    __syncthreads();
    int w = tid >> 6, lane = tid & 63, l15 = lane & 15, quad = lane >> 4;
    fl4 zero = {0.f, 0.f, 0.f, 0.f};
    fl4 acc[8];
#pragma unroll
    for (int i = 0; i < 8; ++i) acc[i] = zero;
    const unsigned short* lrow = &ldsT[w * 16 + l15][quad * 8];
    for (int k0 = 0; k0 < C_IN; k0 += 32) {
        sh8 bf = *(const sh8*)(lrow + k0);
#pragma unroll
        for (int mf = 0; mf < 8; ++mf) {
            sh8 af = *(const sh8*)(W + (size_t)(mf * 16 + l15) * C_IN + k0 + quad * 8);
            acc[mf] = __builtin_amdgcn_mfma_f32_16x16x32_bf16(af, bf, acc[mf], 0, 0, 0);
        }
    }
    int p = p0 + w * 16 + l15;
    if (pr < 2) {
        unsigned short* dst = (pr == 0 ? Qt : Kt) + ((size_t)b * P_TOT + p) * INTER;
#pragma unroll
        for (int mf = 0; mf < 8; ++mf) {
            int o = mf * 16 + quad * 4;
            unsigned short r[4];
#pragma unroll
            for (int j = 0; j < 4; ++j) r[j] = f2bf(acc[mf][j] + bias[o + j]);
            uint2 v;
            v.x = (unsigned)r[0] | ((unsigned)r[1] << 16);
            v.y = (unsigned)r[2] | ((unsigned)r[3] << 16);
            *(uint2*)(dst + o) = v;
        }
    } else {
#pragma unroll
        for (int mf = 0; mf < 8; ++mf) {
            int o = mf * 16 + quad * 4;
#pragma unroll
            for (int j = 0; j < 4; ++j)
                Vn[((size_t)b * INTER + o + j) * P_TOT + p] = f2bf(acc[mf][j] + bias[o + j]);
        }
    }
}

// ---------------- Kernel 2: flash attention (all-bf16 internal buffers).
// grid (36 qtiles, 8 heads, 4 batch), 4 waves x 16 q each.
// Computes S^T = K^T Q (16x16x16 MFMA) so softmaxed P^T in C-layout (row=quad*4+reg=key,
// col=lane&15=q) is bit-identical to the PV MFMA's B-operand layout.
__global__ __launch_bounds__(256) void k_attn(
    const unsigned short* __restrict__ Qt, const unsigned short* __restrict__ Kt,
    const unsigned short* __restrict__ Vn, unsigned short* __restrict__ Ot) {
    int qt = blockIdx.x, h = blockIdx.y, b = blockIdx.z;
    int tid = threadIdx.x, w = tid >> 6, lane = tid & 63;
    int l15 = lane & 15, quad = lane >> 4;
    int q = qt * 64 + w * 16 + l15;
    sh4 qf = *(const sh4*)(Qt + ((size_t)b * P_TOT + q) * INTER + h * HD + quad * 4);
    const unsigned short* kbase = Kt + (size_t)b * P_TOT * INTER + h * HD + quad * 4;
    const unsigned short* vbase = Vn + ((size_t)b * INTER + h * HD + l15) * P_TOT + quad * 4;
    const float scale = 0.25f;             // 1/sqrt(16)
    const float L2E = 1.4426950408889634f; // log2(e)
    float m = -1e30f, l = 0.f;
    fl4 zero = {0.f, 0.f, 0.f, 0.f};
    fl4 o = zero;
    for (int kb = 0; kb < P_TOT / 16; ++kb) {
        int kp = kb * 16;
        sh4 kf = *(const sh4*)(kbase + (size_t)(kp + l15) * INTER);
        sh4 vf = *(const sh4*)(vbase + kp);
        fl4 s = __builtin_amdgcn_mfma_f32_16x16x16bf16_1k(kf, qf, zero, 0, 0, 0);
        float s0 = s[0] * scale, s1 = s[1] * scale, s2 = s[2] * scale, s3 = s[3] * scale;
        float tm = fmaxf(fmaxf(s0, s1), fmaxf(s2, s3));
        tm = fmaxf(tm, __shfl_xor(tm, 16));
        tm = fmaxf(tm, __shfl_xor(tm, 32));
        float mnew = fmaxf(m, tm);
        float alpha = exp2f((m - mnew) * L2E);
        float p0 = exp2f((s0 - mnew) * L2E);
        float p1 = exp2f((s1 - mnew) * L2E);
        float p2 = exp2f((s2 - mnew) * L2E);
        float p3 = exp2f((s3 - mnew) * L2E);
        float ps = p0 + p1 + p2 + p3;
        ps += __shfl_xor(ps, 16);
        ps += __shfl_xor(ps, 32);
        l = l * alpha + ps;
        m = mnew;
        o = o * alpha;
        sh4 pf;
        pf[0] = (short)f2bf(p0);
        pf[1] = (short)f2bf(p1);
        pf[2] = (short)f2bf(p2);
        pf[3] = (short)f2bf(p3);
        o = __builtin_amdgcn_mfma_f32_16x16x16bf16_1k(vf, pf, o, 0, 0, 0);
    }
    float inv = 1.f / l;
    unsigned short r[4];
#pragma unroll
    for (int j = 0; j < 4; ++j) r[j] = f2bf(o[j] * inv);
    uint2 v;
    v.x = (unsigned)r[0] | ((unsigned)r[1] << 16);
    v.y = (unsigned)r[2] | ((unsigned)r[3] << 16);
    *(uint2*)(Ot + ((size_t)b * P_TOT + q) * INTER + h * HD + quad * 4) = v;
}

// ---------------- Kernel 3: output projection + bias + 3 residual adds (f32 out). grid (36, 4)
__global__ __launch_bounds__(256) void k_out(
    const unsigned short* __restrict__ Ot, const unsigned short* __restrict__ Wob,
    const float* __restrict__ bo, const float* __restrict__ rgb,
    const float* __restrict__ depth, const float* __restrict__ rgbd,
    float* __restrict__ out) {
    int nt = blockIdx.x, b = blockIdx.y;
    int tid = threadIdx.x, w = tid >> 6, lane = tid & 63;
    int l15 = lane & 15, quad = lane >> 4;
    int p = nt * 64 + w * 16 + l15;
    fl4 zero = {0.f, 0.f, 0.f, 0.f};
    fl4 acc[16];
#pragma unroll
    for (int i = 0; i < 16; ++i) acc[i] = zero;
    const unsigned short* orow = Ot + ((size_t)b * P_TOT + p) * INTER + quad * 8;
    for (int k0 = 0; k0 < INTER; k0 += 32) {
        sh8 bf = *(const sh8*)(orow + k0);
#pragma unroll
        for (int mf = 0; mf < 16; ++mf) {
            sh8 af = *(const sh8*)(Wob + (size_t)(mf * 16 + l15) * INTER + k0 + quad * 8);
            acc[mf] = __builtin_amdgcn_mfma_f32_16x16x32_bf16(af, bf, acc[mf], 0, 0, 0);
        }
    }
    const size_t outsz = (size_t)4 * C_IN * P_TOT;
#pragma unroll
    for (int mf = 0; mf < 16; ++mf) {
        int o = mf * 16 + quad * 4;
#pragma unroll
        for (int j = 0; j < 4; ++j) {
            size_t idx = ((size_t)b * C_IN + o + j) * P_TOT + p;
            float r = acc[mf][j] + bo[o + j];
            out[idx] = rgb[idx] + r;
            out[outsz + idx] = depth[idx] + r;
            out[2 * outsz + idx] = rgbd[idx] + r;
        }
    }
}

extern "C" void kernel_launch(void* const* d_in, const int* in_sizes, int n_in,
                              void* d_out, int out_size, void* d_ws, size_t ws_size,
                              hipStream_t stream) {
    (void)in_sizes; (void)n_in; (void)out_size; (void)ws_size;
    const float* rgb   = (const float*)d_in[0];
    const float* depth = (const float*)d_in[1];
    const float* rgbd  = (const float*)d_in[2];
    const float* Wq = (const float*)d_in[3];
    const float* bq = (const float*)d_in[4];
    const float* Wk = (const float*)d_in[5];
    const float* bk = (const float*)d_in[6];
    const float* Wv = (const float*)d_in[7];
    const float* bv = (const float*)d_in[8];
    const float* Wo = (const float*)d_in[9];
    const float* bo = (const float*)d_in[10];

    // Scratch plan: Qt/Kt/Vn (bf16, 7.08 MB) live in d_out (28.3 MB f32) and are
    // dead before k_out overwrites d_out. d_ws holds Ot (2.36 MB) + bf16 weights
    // (0.26 MB) = 2.62 MB total.
    float* outp = (float*)d_out;
    unsigned short* Qt = (unsigned short*)d_out;
    unsigned short* Kt = Qt + (size_t)4 * P_TOT * INTER;
    unsigned short* Vn = Kt + (size_t)4 * P_TOT * INTER;
    unsigned short* Ot = (unsigned short*)d_ws;
    unsigned short* Wb = Ot + (size_t)4 * P_TOT * INTER;

    k_prep<<<512, 256, 0, stream>>>(Wq, Wk, Wv, Wo, Wb);
    k_qkv<<<dim3(36, 12), 256, 0, stream>>>(rgb, depth, rgbd, Wb, bq, bk, bv, Qt, Kt, Vn);
    k_attn<<<dim3(36, NH, 4), 256, 0, stream>>>(Qt, Kt, Vn, Ot);
    k_out<<<dim3(36, 4), 256, 0, stream>>>(Ot, Wb + 3 * 32768, bo, rgb, depth, rgbd, outp);
}

// Round 4
// 269.399 us; speedup vs baseline: 1.2969x; 1.2969x over previous
//
#include <hip/hip_runtime.h>
#include <stdint.h>

#define P_TOT 2304
#define C_IN  256
#define INTER 128
#define NH    8
#define HD    16
// fold 1/sqrt(16) * log2(e) into Q so attention does exp2(S) directly
#define QSCALE 0.36067376022224087f

typedef short sh4 __attribute__((ext_vector_type(4)));
typedef short sh8 __attribute__((ext_vector_type(8)));
typedef float fl4 __attribute__((ext_vector_type(4)));

static __device__ __forceinline__ unsigned short f2bf(float f) {
    union { float f; unsigned u; } v; v.f = f;
    return (unsigned short)((v.u + 0x7fffu + ((v.u >> 16) & 1u)) >> 16);
}
// pack two floats as bf16 pair (round-half-up) in ONE v_perm + 2 adds
static __device__ __forceinline__ unsigned pack_bf2(float a, float b) {
    union { float f; unsigned u; } x, y; x.f = a; y.f = b;
    return __builtin_amdgcn_perm(y.u + 0x8000u, x.u + 0x8000u, 0x07060302u);
}

// ---------------- Kernel 0: weights f32 -> bf16. Wb: [Wq][Wk][Wv][Wo] 32768 each.
__global__ __launch_bounds__(256) void k_prep(
    const float* __restrict__ Wq, const float* __restrict__ Wk,
    const float* __restrict__ Wv, const float* __restrict__ Wo,
    unsigned short* __restrict__ Wb) {
    int i = blockIdx.x * 256 + threadIdx.x;
    int seg = i >> 15, off = i & 32767;
    const float* s = (seg == 0 ? Wq : (seg == 1 ? Wk : (seg == 2 ? Wv : Wo)));
    Wb[i] = f2bf(s[off]);
}

// ---------------- Kernel 1: QKV projection, LDS-free (direct-global B-frags).
// grid (36 p-tiles, 12 = pr*4+b), 256 thr. Q (pre-scaled by QSCALE), K head-major
// [b][h][p][16]; V [b][h][d][P].
__global__ __launch_bounds__(256) void k_qkv(
    const float* __restrict__ rgb, const float* __restrict__ depth,
    const float* __restrict__ rgbd, const unsigned short* __restrict__ Wb,
    const float* __restrict__ bq, const float* __restrict__ bk,
    const float* __restrict__ bv,
    unsigned short* __restrict__ Qt, unsigned short* __restrict__ Kt,
    unsigned short* __restrict__ Vn) {
    int nt = blockIdx.x, pb = blockIdx.y;
    int pr = pb >> 2, b = pb & 3;
    const unsigned short* W = Wb + pr * (INTER * C_IN);
    const float* bias = (pr == 0 ? bq : (pr == 1 ? bk : bv));
    const float* X = (pr == 0 ? rgb : (pr == 1 ? depth : rgbd)) + (size_t)b * C_IN * P_TOT;
    int tid = threadIdx.x, w = tid >> 6, lane = tid & 63;
    int l15 = lane & 15, quad = lane >> 4;
    int p = nt * 64 + w * 16 + l15;
    fl4 zero = {0.f, 0.f, 0.f, 0.f};
    fl4 acc[8];
#pragma unroll
    for (int i = 0; i < 8; ++i) acc[i] = zero;
    const float* xcol = X + p;
    for (int k0 = 0; k0 < C_IN; k0 += 32) {
        int cb = k0 + quad * 8;
        unsigned u[8];
#pragma unroll
        for (int j = 0; j < 8; ++j) {
            union { float f; unsigned uu; } t;
            t.f = xcol[(size_t)(cb + j) * P_TOT];
            u[j] = t.uu;
        }
        sh8 bfr;
        unsigned* bu = (unsigned*)&bfr;
        bu[0] = __builtin_amdgcn_perm(u[1] + 0x8000u, u[0] + 0x8000u, 0x07060302u);
        bu[1] = __builtin_amdgcn_perm(u[3] + 0x8000u, u[2] + 0x8000u, 0x07060302u);
        bu[2] = __builtin_amdgcn_perm(u[5] + 0x8000u, u[4] + 0x8000u, 0x07060302u);
        bu[3] = __builtin_amdgcn_perm(u[7] + 0x8000u, u[6] + 0x8000u, 0x07060302u);
#pragma unroll
        for (int mf = 0; mf < 8; ++mf) {
            sh8 af = *(const sh8*)(W + (size_t)(mf * 16 + l15) * C_IN + k0 + quad * 8);
            acc[mf] = __builtin_amdgcn_mfma_f32_16x16x32_bf16(af, bfr, acc[mf], 0, 0, 0);
        }
    }
    if (pr < 2) {
        unsigned short* dst0 = (pr == 0 ? Qt : Kt);
        float sc = (pr == 0 ? QSCALE : 1.0f);
#pragma unroll
        for (int mf = 0; mf < 8; ++mf) {
            int o = mf * 16 + quad * 4;
            float v0 = (acc[mf][0] + bias[o + 0]) * sc;
            float v1 = (acc[mf][1] + bias[o + 1]) * sc;
            float v2 = (acc[mf][2] + bias[o + 2]) * sc;
            float v3 = (acc[mf][3] + bias[o + 3]) * sc;
            uint2 v;
            v.x = pack_bf2(v0, v1);
            v.y = pack_bf2(v2, v3);
            *(uint2*)(dst0 + ((size_t)(b * NH + mf) * P_TOT + p) * HD + quad * 4) = v;
        }
    } else {
#pragma unroll
        for (int mf = 0; mf < 8; ++mf) {
            int o = mf * 16 + quad * 4;
#pragma unroll
            for (int j = 0; j < 4; ++j)
                Vn[((size_t)(b * NH + mf) * HD + quad * 4 + j) * P_TOT + p] =
                    f2bf(acc[mf][j] + bias[o + j]);
        }
    }
}

// ---------------- Kernel 2: flash attention, NO online max (scores provably < ~3;
// softmax shift-invariant -> fixed shift 0, exp2 direct since Q pre-scaled by log2e).
// grid (18 q-tiles, 8 h, 4 b), 4 waves x 32 q (2 streams sharing K/V loads).
// S^T = K^T Q: C-layout (row=key=quad*4+reg, col=q=lane&15) == PV B-operand layout.
__global__ __launch_bounds__(256) void k_attn(
    const unsigned short* __restrict__ Qt, const unsigned short* __restrict__ Kt,
    const unsigned short* __restrict__ Vn, unsigned short* __restrict__ Ot) {
    int qt = blockIdx.x, h = blockIdx.y, b = blockIdx.z;
    int tid = threadIdx.x, w = tid >> 6, lane = tid & 63;
    int l15 = lane & 15, quad = lane >> 4;
    int bh = b * NH + h;
    int q0 = qt * 128 + w * 32 + l15;
    const unsigned short* qb = Qt + (size_t)bh * P_TOT * HD;
    sh4 qf0 = *(const sh4*)(qb + (size_t)q0 * HD + quad * 4);
    sh4 qf1 = *(const sh4*)(qb + (size_t)(q0 + 16) * HD + quad * 4);
    const unsigned short* kb = Kt + (size_t)bh * P_TOT * HD + quad * 4;
    const unsigned short* vb = Vn + ((size_t)bh * HD + l15) * P_TOT + quad * 4;
    fl4 zero = {0.f, 0.f, 0.f, 0.f};
    fl4 o0 = zero, o1 = zero;
    float ls0 = 0.f, ls1 = 0.f;
    for (int kp = 0; kp < P_TOT; kp += 16) {
        sh4 kf = *(const sh4*)(kb + (size_t)(kp + l15) * HD);
        sh4 vf = *(const sh4*)(vb + kp);
        fl4 s0 = __builtin_amdgcn_mfma_f32_16x16x16bf16_1k(kf, qf0, zero, 0, 0, 0);
        fl4 s1 = __builtin_amdgcn_mfma_f32_16x16x16bf16_1k(kf, qf1, zero, 0, 0, 0);
        float e00 = exp2f(s0[0]), e01 = exp2f(s0[1]);
        float e02 = exp2f(s0[2]), e03 = exp2f(s0[3]);
        float e10 = exp2f(s1[0]), e11 = exp2f(s1[1]);
        float e12 = exp2f(s1[2]), e13 = exp2f(s1[3]);
        ls0 += (e00 + e01) + (e02 + e03);
        ls1 += (e10 + e11) + (e12 + e13);
        sh4 pf0, pf1;
        ((unsigned*)&pf0)[0] = pack_bf2(e00, e01);
        ((unsigned*)&pf0)[1] = pack_bf2(e02, e03);
        ((unsigned*)&pf1)[0] = pack_bf2(e10, e11);
        ((unsigned*)&pf1)[1] = pack_bf2(e12, e13);
        o0 = __builtin_amdgcn_mfma_f32_16x16x16bf16_1k(vf, pf0, o0, 0, 0, 0);
        o1 = __builtin_amdgcn_mfma_f32_16x16x16bf16_1k(vf, pf1, o1, 0, 0, 0);
    }
    ls0 += __shfl_xor(ls0, 16); ls0 += __shfl_xor(ls0, 32);
    ls1 += __shfl_xor(ls1, 16); ls1 += __shfl_xor(ls1, 32);
    float inv0 = 1.f / ls0, inv1 = 1.f / ls1;
    unsigned short* ob = Ot + (size_t)bh * P_TOT * HD;
    uint2 v0, v1;
    v0.x = pack_bf2(o0[0] * inv0, o0[1] * inv0);
    v0.y = pack_bf2(o0[2] * inv0, o0[3] * inv0);
    v1.x = pack_bf2(o1[0] * inv1, o1[1] * inv1);
    v1.y = pack_bf2(o1[2] * inv1, o1[3] * inv1);
    *(uint2*)(ob + (size_t)q0 * HD + quad * 4) = v0;
    *(uint2*)(ob + (size_t)(q0 + 16) * HD + quad * 4) = v1;
}

// ---------------- Kernel 3: output projection + bias + 3 residuals (f32).
// grid (72 p-tiles, 4 b), 128 thr (2 waves) -> 288 blocks (was 144 < 256 CUs).
__global__ __launch_bounds__(128) void k_out(
    const unsigned short* __restrict__ Ot, const unsigned short* __restrict__ Wob,
    const float* __restrict__ bo, const float* __restrict__ rgb,
    const float* __restrict__ depth, const float* __restrict__ rgbd,
    float* __restrict__ out) {
    int nt = blockIdx.x, b = blockIdx.y;
    int tid = threadIdx.x, w = tid >> 6, lane = tid & 63;
    int l15 = lane & 15, quad = lane >> 4;
    int p = nt * 32 + w * 16 + l15;
    fl4 zero = {0.f, 0.f, 0.f, 0.f};
    fl4 acc[16];
#pragma unroll
    for (int i = 0; i < 16; ++i) acc[i] = zero;
#pragma unroll
    for (int k0 = 0; k0 < INTER; k0 += 32) {
        int h = (k0 >> 4) + (quad >> 1);
        int doff = 8 * (quad & 1);
        sh8 bfr = *(const sh8*)(Ot + ((size_t)(b * NH + h) * P_TOT + p) * HD + doff);
#pragma unroll
        for (int mf = 0; mf < 16; ++mf) {
            sh8 af = *(const sh8*)(Wob + (size_t)(mf * 16 + l15) * INTER + k0 + quad * 8);
            acc[mf] = __builtin_amdgcn_mfma_f32_16x16x32_bf16(af, bfr, acc[mf], 0, 0, 0);
        }
    }
    const size_t outsz = (size_t)4 * C_IN * P_TOT;
#pragma unroll
    for (int mf = 0; mf < 16; ++mf) {
        int o = mf * 16 + quad * 4;
#pragma unroll
        for (int j = 0; j < 4; ++j) {
            size_t idx = ((size_t)b * C_IN + o + j) * P_TOT + p;
            float r = acc[mf][j] + bo[o + j];
            out[idx] = rgb[idx] + r;
            out[outsz + idx] = depth[idx] + r;
            out[2 * outsz + idx] = rgbd[idx] + r;
        }
    }
}

extern "C" void kernel_launch(void* const* d_in, const int* in_sizes, int n_in,
                              void* d_out, int out_size, void* d_ws, size_t ws_size,
                              hipStream_t stream) {
    (void)in_sizes; (void)n_in; (void)out_size; (void)ws_size;
    const float* rgb   = (const float*)d_in[0];
    const float* depth = (const float*)d_in[1];
    const float* rgbd  = (const float*)d_in[2];
    const float* Wq = (const float*)d_in[3];
    const float* bq = (const float*)d_in[4];
    const float* Wk = (const float*)d_in[5];
    const float* bk = (const float*)d_in[6];
    const float* Wv = (const float*)d_in[7];
    const float* bv = (const float*)d_in[8];
    const float* Wo = (const float*)d_in[9];
    const float* bo = (const float*)d_in[10];

    // Qt/Kt/Vn (bf16, 7.08 MB) live in d_out (28.3 MB f32), dead before k_out
    // overwrites it. d_ws: Ot (2.36 MB) + Wb (0.26 MB).
    float* outp = (float*)d_out;
    unsigned short* Qt = (unsigned short*)d_out;
    unsigned short* Kt = Qt + (size_t)4 * P_TOT * INTER;
    unsigned short* Vn = Kt + (size_t)4 * P_TOT * INTER;
    unsigned short* Ot = (unsigned short*)d_ws;
    unsigned short* Wb = Ot + (size_t)4 * P_TOT * INTER;

    k_prep<<<512, 256, 0, stream>>>(Wq, Wk, Wv, Wo, Wb);
    k_qkv<<<dim3(36, 12), 256, 0, stream>>>(rgb, depth, rgbd, Wb, bq, bk, bv, Qt, Kt, Vn);
    k_attn<<<dim3(18, NH, 4), 256, 0, stream>>>(Qt, Kt, Vn, Ot);
    k_out<<<dim3(72, 4), 128, 0, stream>>>(Ot, Wb + 3 * 32768, bo, rgb, depth, rgbd, outp);
}

// Round 5
// 198.424 us; speedup vs baseline: 1.7608x; 1.3577x over previous
//
#include <hip/hip_runtime.h>
#include <stdint.h>

#define P_TOT 2304
#define C_IN  256
#define INTER 128
#define NH    8
#define HD    16
// fold 1/sqrt(16) * log2(e) into Q so attention does exp2(S) directly
#define QSCALE 0.36067376022224087f

typedef short sh4 __attribute__((ext_vector_type(4)));
typedef short sh8 __attribute__((ext_vector_type(8)));
typedef float fl4 __attribute__((ext_vector_type(4)));

static __device__ __forceinline__ unsigned short f2bf(float f) {
    union { float f; unsigned u; } v; v.f = f;
    return (unsigned short)((v.u + 0x7fffu + ((v.u >> 16) & 1u)) >> 16);
}
// pack two floats as bf16 pair, round-half-up (1 perm + 2 adds)
static __device__ __forceinline__ unsigned pack_bf2(float a, float b) {
    union { float f; unsigned u; } x, y; x.f = a; y.f = b;
    return __builtin_amdgcn_perm(y.u + 0x8000u, x.u + 0x8000u, 0x07060302u);
}
// truncating pack (1 perm). Downward bias cancels in softmax normalization.
static __device__ __forceinline__ unsigned pack_bf2_trunc(float a, float b) {
    union { float f; unsigned u; } x, y; x.f = a; y.f = b;
    return __builtin_amdgcn_perm(y.u, x.u, 0x07060302u);
}

// ---------------- Kernel 0: weights f32 -> bf16. Wb: [Wq][Wk][Wv][Wo] 32768 each.
__global__ __launch_bounds__(256) void k_prep(
    const float* __restrict__ Wq, const float* __restrict__ Wk,
    const float* __restrict__ Wv, const float* __restrict__ Wo,
    unsigned short* __restrict__ Wb) {
    int i = blockIdx.x * 256 + threadIdx.x;
    int seg = i >> 15, off = i & 32767;
    const float* s = (seg == 0 ? Wq : (seg == 1 ? Wk : (seg == 2 ? Wv : Wo)));
    Wb[i] = f2bf(s[off]);
}

// ---------------- Kernel 1: QKV projection, LDS-free (direct-global B-frags).
// grid (36 p-tiles, 12 = pr*4+b), 256 thr. Q (pre-scaled by QSCALE), K head-major
// [b][h][p][16]; V [b][h][d][P].
__global__ __launch_bounds__(256) void k_qkv(
    const float* __restrict__ rgb, const float* __restrict__ depth,
    const float* __restrict__ rgbd, const unsigned short* __restrict__ Wb,
    const float* __restrict__ bq, const float* __restrict__ bk,
    const float* __restrict__ bv,
    unsigned short* __restrict__ Qt, unsigned short* __restrict__ Kt,
    unsigned short* __restrict__ Vn) {
    int nt = blockIdx.x, pb = blockIdx.y;
    int pr = pb >> 2, b = pb & 3;
    const unsigned short* W = Wb + pr * (INTER * C_IN);
    const float* bias = (pr == 0 ? bq : (pr == 1 ? bk : bv));
    const float* X = (pr == 0 ? rgb : (pr == 1 ? depth : rgbd)) + (size_t)b * C_IN * P_TOT;
    int tid = threadIdx.x, w = tid >> 6, lane = tid & 63;
    int l15 = lane & 15, quad = lane >> 4;
    int p = nt * 64 + w * 16 + l15;
    fl4 zero = {0.f, 0.f, 0.f, 0.f};
    fl4 acc[8];
#pragma unroll
    for (int i = 0; i < 8; ++i) acc[i] = zero;
    const float* xcol = X + p;
    for (int k0 = 0; k0 < C_IN; k0 += 32) {
        int cb = k0 + quad * 8;
        unsigned u[8];
#pragma unroll
        for (int j = 0; j < 8; ++j) {
            union { float f; unsigned uu; } t;
            t.f = xcol[(size_t)(cb + j) * P_TOT];
            u[j] = t.uu;
        }
        sh8 bfr;
        unsigned* bu = (unsigned*)&bfr;
        bu[0] = __builtin_amdgcn_perm(u[1] + 0x8000u, u[0] + 0x8000u, 0x07060302u);
        bu[1] = __builtin_amdgcn_perm(u[3] + 0x8000u, u[2] + 0x8000u, 0x07060302u);
        bu[2] = __builtin_amdgcn_perm(u[5] + 0x8000u, u[4] + 0x8000u, 0x07060302u);
        bu[3] = __builtin_amdgcn_perm(u[7] + 0x8000u, u[6] + 0x8000u, 0x07060302u);
#pragma unroll
        for (int mf = 0; mf < 8; ++mf) {
            sh8 af = *(const sh8*)(W + (size_t)(mf * 16 + l15) * C_IN + k0 + quad * 8);
            acc[mf] = __builtin_amdgcn_mfma_f32_16x16x32_bf16(af, bfr, acc[mf], 0, 0, 0);
        }
    }
    if (pr < 2) {
        unsigned short* dst0 = (pr == 0 ? Qt : Kt);
        float sc = (pr == 0 ? QSCALE : 1.0f);
#pragma unroll
        for (int mf = 0; mf < 8; ++mf) {
            int o = mf * 16 + quad * 4;
            float v0 = (acc[mf][0] + bias[o + 0]) * sc;
            float v1 = (acc[mf][1] + bias[o + 1]) * sc;
            float v2 = (acc[mf][2] + bias[o + 2]) * sc;
            float v3 = (acc[mf][3] + bias[o + 3]) * sc;
            uint2 v;
            v.x = pack_bf2(v0, v1);
            v.y = pack_bf2(v2, v3);
            *(uint2*)(dst0 + ((size_t)(b * NH + mf) * P_TOT + p) * HD + quad * 4) = v;
        }
    } else {
#pragma unroll
        for (int mf = 0; mf < 8; ++mf) {
            int o = mf * 16 + quad * 4;
#pragma unroll
            for (int j = 0; j < 4; ++j)
                Vn[((size_t)(b * NH + mf) * HD + quad * 4 + j) * P_TOT + p] =
                    f2bf(acc[mf][j] + bias[o + j]);
        }
    }
}

// ---------------- Kernel 2: attention, no-max softmax (scores bounded ~|3|),
// raw v_exp_f32 via builtin. grid (18 q-tiles, 8 h, 4 b), 512 thr = 8 waves:
// waves 0-3 keys [0,1152), waves 4-7 keys [1152,2304), same 32 q per wave pair;
// partials (o,l) combined through LDS (split is exact: fixed shift 0 => sums
// are associative). S^T = K^T Q: C-layout == PV B-operand layout.
__global__ __launch_bounds__(512) void k_attn(
    const unsigned short* __restrict__ Qt, const unsigned short* __restrict__ Kt,
    const unsigned short* __restrict__ Vn, unsigned short* __restrict__ Ot) {
    __shared__ float ldsc[10][256];
    int qt = blockIdx.x, h = blockIdx.y, b = blockIdx.z;
    int tid = threadIdx.x, w = tid >> 6, lane = tid & 63;
    int l15 = lane & 15, quad = lane >> 4;
    int bh = b * NH + h;
    int q0 = qt * 128 + (w & 3) * 32 + l15;
    int ko = (w >> 2) * (P_TOT / 2);
    const unsigned short* qb = Qt + (size_t)bh * P_TOT * HD;
    sh4 qf0 = *(const sh4*)(qb + (size_t)q0 * HD + quad * 4);
    sh4 qf1 = *(const sh4*)(qb + (size_t)(q0 + 16) * HD + quad * 4);
    const unsigned short* kb = Kt + (size_t)bh * P_TOT * HD + quad * 4;
    const unsigned short* vb = Vn + ((size_t)bh * HD + l15) * P_TOT + quad * 4;
    fl4 zero = {0.f, 0.f, 0.f, 0.f};
    fl4 o0 = zero, o1 = zero;
    float ls0 = 0.f, ls1 = 0.f;
    for (int kp = ko; kp < ko + P_TOT / 2; kp += 16) {
        sh4 kf = *(const sh4*)(kb + (size_t)(kp + l15) * HD);
        sh4 vf = *(const sh4*)(vb + kp);
        fl4 s0 = __builtin_amdgcn_mfma_f32_16x16x16bf16_1k(kf, qf0, zero, 0, 0, 0);
        fl4 s1 = __builtin_amdgcn_mfma_f32_16x16x16bf16_1k(kf, qf1, zero, 0, 0, 0);
        float e00 = __builtin_amdgcn_exp2f(s0[0]), e01 = __builtin_amdgcn_exp2f(s0[1]);
        float e02 = __builtin_amdgcn_exp2f(s0[2]), e03 = __builtin_amdgcn_exp2f(s0[3]);
        float e10 = __builtin_amdgcn_exp2f(s1[0]), e11 = __builtin_amdgcn_exp2f(s1[1]);
        float e12 = __builtin_amdgcn_exp2f(s1[2]), e13 = __builtin_amdgcn_exp2f(s1[3]);
        ls0 += (e00 + e01) + (e02 + e03);
        ls1 += (e10 + e11) + (e12 + e13);
        sh4 pf0, pf1;
        ((unsigned*)&pf0)[0] = pack_bf2_trunc(e00, e01);
        ((unsigned*)&pf0)[1] = pack_bf2_trunc(e02, e03);
        ((unsigned*)&pf1)[0] = pack_bf2_trunc(e10, e11);
        ((unsigned*)&pf1)[1] = pack_bf2_trunc(e12, e13);
        o0 = __builtin_amdgcn_mfma_f32_16x16x16bf16_1k(vf, pf0, o0, 0, 0, 0);
        o1 = __builtin_amdgcn_mfma_f32_16x16x16bf16_1k(vf, pf1, o1, 0, 0, 0);
    }
    int widx = (w & 3) * 64 + lane;
    if (w >= 4) {
#pragma unroll
        for (int j = 0; j < 4; ++j) {
            ldsc[j][widx] = o0[j];
            ldsc[4 + j][widx] = o1[j];
        }
        ldsc[8][widx] = ls0;
        ldsc[9][widx] = ls1;
    }
    __syncthreads();
    if (w >= 4) return;
#pragma unroll
    for (int j = 0; j < 4; ++j) {
        o0[j] += ldsc[j][widx];
        o1[j] += ldsc[4 + j][widx];
    }
    ls0 += ldsc[8][widx];
    ls1 += ldsc[9][widx];
    ls0 += __shfl_xor(ls0, 16); ls0 += __shfl_xor(ls0, 32);
    ls1 += __shfl_xor(ls1, 16); ls1 += __shfl_xor(ls1, 32);
    float inv0 = 1.f / ls0, inv1 = 1.f / ls1;
    unsigned short* ob = Ot + (size_t)bh * P_TOT * HD;
    uint2 v0, v1;
    v0.x = pack_bf2(o0[0] * inv0, o0[1] * inv0);
    v0.y = pack_bf2(o0[2] * inv0, o0[3] * inv0);
    v1.x = pack_bf2(o1[0] * inv1, o1[1] * inv1);
    v1.y = pack_bf2(o1[2] * inv1, o1[3] * inv1);
    *(uint2*)(ob + (size_t)q0 * HD + quad * 4) = v0;
    *(uint2*)(ob + (size_t)(q0 + 16) * HD + quad * 4) = v1;
}

// ---------------- Kernel 3: output projection + bias + 3 residuals (f32).
// grid (144 p-tiles of 16, 4 b), 256 thr; wave w owns channel band [w*64, w*64+64).
// 2304 waves = 9 waves/CU (was 0.56/SIMD).
__global__ __launch_bounds__(256) void k_out(
    const unsigned short* __restrict__ Ot, const unsigned short* __restrict__ Wob,
    const float* __restrict__ bo, const float* __restrict__ rgb,
    const float* __restrict__ depth, const float* __restrict__ rgbd,
    float* __restrict__ out) {
    int nt = blockIdx.x, b = blockIdx.y;
    int tid = threadIdx.x, w = tid >> 6, lane = tid & 63;
    int l15 = lane & 15, quad = lane >> 4;
    int p = nt * 16 + l15;
    fl4 zero = {0.f, 0.f, 0.f, 0.f};
    fl4 acc[4];
#pragma unroll
    for (int i = 0; i < 4; ++i) acc[i] = zero;
#pragma unroll
    for (int k0 = 0; k0 < INTER; k0 += 32) {
        int h = (k0 >> 4) + (quad >> 1);
        int doff = 8 * (quad & 1);
        sh8 bfr = *(const sh8*)(Ot + ((size_t)(b * NH + h) * P_TOT + p) * HD + doff);
#pragma unroll
        for (int mf2 = 0; mf2 < 4; ++mf2) {
            int mf = w * 4 + mf2;
            sh8 af = *(const sh8*)(Wob + (size_t)(mf * 16 + l15) * INTER + k0 + quad * 8);
            acc[mf2] = __builtin_amdgcn_mfma_f32_16x16x32_bf16(af, bfr, acc[mf2], 0, 0, 0);
        }
    }
    const size_t outsz = (size_t)4 * C_IN * P_TOT;
#pragma unroll
    for (int mf2 = 0; mf2 < 4; ++mf2) {
        int o = (w * 4 + mf2) * 16 + quad * 4;
#pragma unroll
        for (int j = 0; j < 4; ++j) {
            size_t idx = ((size_t)b * C_IN + o + j) * P_TOT + p;
            float r = acc[mf2][j] + bo[o + j];
            out[idx] = rgb[idx] + r;
            out[outsz + idx] = depth[idx] + r;
            out[2 * outsz + idx] = rgbd[idx] + r;
        }
    }
}

extern "C" void kernel_launch(void* const* d_in, const int* in_sizes, int n_in,
                              void* d_out, int out_size, void* d_ws, size_t ws_size,
                              hipStream_t stream) {
    (void)in_sizes; (void)n_in; (void)out_size; (void)ws_size;
    const float* rgb   = (const float*)d_in[0];
    const float* depth = (const float*)d_in[1];
    const float* rgbd  = (const float*)d_in[2];
    const float* Wq = (const float*)d_in[3];
    const float* bq = (const float*)d_in[4];
    const float* Wk = (const float*)d_in[5];
    const float* bk = (const float*)d_in[6];
    const float* Wv = (const float*)d_in[7];
    const float* bv = (const float*)d_in[8];
    const float* Wo = (const float*)d_in[9];
    const float* bo = (const float*)d_in[10];

    // Qt/Kt/Vn (bf16, 7.08 MB) live in d_out (28.3 MB f32), dead before k_out
    // overwrites it. d_ws: Ot (2.36 MB) + Wb (0.26 MB).
    float* outp = (float*)d_out;
    unsigned short* Qt = (unsigned short*)d_out;
    unsigned short* Kt = Qt + (size_t)4 * P_TOT * INTER;
    unsigned short* Vn = Kt + (size_t)4 * P_TOT * INTER;
    unsigned short* Ot = (unsigned short*)d_ws;
    unsigned short* Wb = Ot + (size_t)4 * P_TOT * INTER;

    k_prep<<<512, 256, 0, stream>>>(Wq, Wk, Wv, Wo, Wb);
    k_qkv<<<dim3(36, 12), 256, 0, stream>>>(rgb, depth, rgbd, Wb, bq, bk, bv, Qt, Kt, Vn);
    k_attn<<<dim3(18, NH, 4), 512, 0, stream>>>(Qt, Kt, Vn, Ot);
    k_out<<<dim3(144, 4), 256, 0, stream>>>(Ot, Wb + 3 * 32768, bo, rgb, depth, rgbd, outp);
}

// Round 6
// 173.515 us; speedup vs baseline: 2.0136x; 1.1436x over previous
//
#include <hip/hip_runtime.h>
#include <stdint.h>

#define P_TOT 2304
#define C_IN  256
#define INTER 128
#define NH    8
#define HD    16
// fold 1/sqrt(16) * log2(e) into Q so attention does exp2(S) directly
#define QSCALE 0.36067376022224087f

typedef short sh4 __attribute__((ext_vector_type(4)));
typedef short sh8 __attribute__((ext_vector_type(8)));
typedef float fl4 __attribute__((ext_vector_type(4)));

static __device__ __forceinline__ unsigned short f2bf(float f) {
    union { float f; unsigned u; } v; v.f = f;
    return (unsigned short)((v.u + 0x7fffu + ((v.u >> 16) & 1u)) >> 16);
}
// pack two floats as bf16 pair, round-half-up (1 perm + 2 adds)
static __device__ __forceinline__ unsigned pack_bf2(float a, float b) {
    union { float f; unsigned u; } x, y; x.f = a; y.f = b;
    return __builtin_amdgcn_perm(y.u + 0x8000u, x.u + 0x8000u, 0x07060302u);
}
// truncating pack (1 perm). Downward bias cancels in softmax normalization.
static __device__ __forceinline__ unsigned pack_bf2_trunc(float a, float b) {
    union { float f; unsigned u; } x, y; x.f = a; y.f = b;
    return __builtin_amdgcn_perm(y.u, x.u, 0x07060302u);
}

// ---------------- Kernel 0: weights f32 -> bf16. Wb: [Wq][Wk][Wv][Wo] 32768 each.
__global__ __launch_bounds__(256) void k_prep(
    const float* __restrict__ Wq, const float* __restrict__ Wk,
    const float* __restrict__ Wv, const float* __restrict__ Wo,
    unsigned short* __restrict__ Wb) {
    int i = blockIdx.x * 256 + threadIdx.x;
    int seg = i >> 15, off = i & 32767;
    const float* s = (seg == 0 ? Wq : (seg == 1 ? Wk : (seg == 2 ? Wv : Wo)));
    Wb[i] = f2bf(s[off]);
}

// ---------------- Kernel 1: QKV projection, LDS-free. grid (72 p-tiles of 32,
// 12 = pr*4+b), 128 thr (2 waves). Q (pre-scaled), K head-major [b][h][p][16];
// V [b][h][d][P] via operand-swapped MFMA (row=p) -> ushort4 stores.
__global__ __launch_bounds__(128) void k_qkv(
    const float* __restrict__ rgb, const float* __restrict__ depth,
    const float* __restrict__ rgbd, const unsigned short* __restrict__ Wb,
    const float* __restrict__ bq, const float* __restrict__ bk,
    const float* __restrict__ bv,
    unsigned short* __restrict__ Qt, unsigned short* __restrict__ Kt,
    unsigned short* __restrict__ Vn) {
    int nt = blockIdx.x, pb = blockIdx.y;
    int pr = pb >> 2, b = pb & 3;
    const unsigned short* W = Wb + pr * (INTER * C_IN);
    const float* bias = (pr == 0 ? bq : (pr == 1 ? bk : bv));
    const float* X = (pr == 0 ? rgb : (pr == 1 ? depth : rgbd)) + (size_t)b * C_IN * P_TOT;
    int tid = threadIdx.x, w = tid >> 6, lane = tid & 63;
    int l15 = lane & 15, quad = lane >> 4;
    int p = nt * 32 + w * 16 + l15;
    fl4 zero = {0.f, 0.f, 0.f, 0.f};
    fl4 acc[8];
#pragma unroll
    for (int i = 0; i < 8; ++i) acc[i] = zero;
    const float* xcol = X + p;
    if (pr < 2) {
#pragma unroll
        for (int k0 = 0; k0 < C_IN; k0 += 32) {
            int cb = k0 + quad * 8;
            unsigned u[8];
#pragma unroll
            for (int j = 0; j < 8; ++j) {
                union { float f; unsigned uu; } t;
                t.f = xcol[(size_t)(cb + j) * P_TOT];
                u[j] = t.uu;
            }
            sh8 bfr;
            unsigned* bu = (unsigned*)&bfr;
            bu[0] = __builtin_amdgcn_perm(u[1] + 0x8000u, u[0] + 0x8000u, 0x07060302u);
            bu[1] = __builtin_amdgcn_perm(u[3] + 0x8000u, u[2] + 0x8000u, 0x07060302u);
            bu[2] = __builtin_amdgcn_perm(u[5] + 0x8000u, u[4] + 0x8000u, 0x07060302u);
            bu[3] = __builtin_amdgcn_perm(u[7] + 0x8000u, u[6] + 0x8000u, 0x07060302u);
#pragma unroll
            for (int mf = 0; mf < 8; ++mf) {
                sh8 af = *(const sh8*)(W + (size_t)(mf * 16 + l15) * C_IN + k0 + quad * 8);
                acc[mf] = __builtin_amdgcn_mfma_f32_16x16x32_bf16(af, bfr, acc[mf], 0, 0, 0);
            }
        }
        unsigned short* dst0 = (pr == 0 ? Qt : Kt);
        float sc = (pr == 0 ? QSCALE : 1.0f);
#pragma unroll
        for (int mf = 0; mf < 8; ++mf) {
            float4 bb = *(const float4*)(bias + mf * 16 + quad * 4);
            uint2 v;
            v.x = pack_bf2((acc[mf][0] + bb.x) * sc, (acc[mf][1] + bb.y) * sc);
            v.y = pack_bf2((acc[mf][2] + bb.z) * sc, (acc[mf][3] + bb.w) * sc);
            *(uint2*)(dst0 + ((size_t)(b * NH + mf) * P_TOT + p) * HD + quad * 4) = v;
        }
    } else {
#pragma unroll
        for (int k0 = 0; k0 < C_IN; k0 += 32) {
            int cb = k0 + quad * 8;
            unsigned u[8];
#pragma unroll
            for (int j = 0; j < 8; ++j) {
                union { float f; unsigned uu; } t;
                t.f = xcol[(size_t)(cb + j) * P_TOT];
                u[j] = t.uu;
            }
            sh8 bfr;
            unsigned* bu = (unsigned*)&bfr;
            bu[0] = __builtin_amdgcn_perm(u[1] + 0x8000u, u[0] + 0x8000u, 0x07060302u);
            bu[1] = __builtin_amdgcn_perm(u[3] + 0x8000u, u[2] + 0x8000u, 0x07060302u);
            bu[2] = __builtin_amdgcn_perm(u[5] + 0x8000u, u[4] + 0x8000u, 0x07060302u);
            bu[3] = __builtin_amdgcn_perm(u[7] + 0x8000u, u[6] + 0x8000u, 0x07060302u);
#pragma unroll
            for (int mf = 0; mf < 8; ++mf) {
                sh8 af = *(const sh8*)(W + (size_t)(mf * 16 + l15) * C_IN + k0 + quad * 8);
                // swapped: C col = W-row (channel), C row = p offset
                acc[mf] = __builtin_amdgcn_mfma_f32_16x16x32_bf16(bfr, af, acc[mf], 0, 0, 0);
            }
        }
        int pv = nt * 32 + w * 16 + quad * 4;
#pragma unroll
        for (int mf = 0; mf < 8; ++mf) {
            float bb = bias[mf * 16 + l15];
            uint2 v;
            v.x = pack_bf2(acc[mf][0] + bb, acc[mf][1] + bb);
            v.y = pack_bf2(acc[mf][2] + bb, acc[mf][3] + bb);
            *(uint2*)(Vn + ((size_t)(b * NH + mf) * HD + l15) * P_TOT + pv) = v;
        }
    }
}

// ---------------- Kernel 2: attention, no-max softmax (scores bounded ~|3|),
// raw v_exp_f32. grid (36 q-tiles of 64, 8 h, 4 b) = 1152 blocks, 256 thr = 4
// waves; each wave: same 64 q (4 streams), its own quarter of the 2304 keys;
// partials combined via LDS (exact: fixed shift 0 => plain sums).
// S^T = K^T Q: C-layout == PV B-operand layout.
__global__ __launch_bounds__(256) void k_attn(
    const unsigned short* __restrict__ Qt, const unsigned short* __restrict__ Kt,
    const unsigned short* __restrict__ Vn, unsigned short* __restrict__ Ot) {
    __shared__ fl4 ldsO[4][3][64];
    __shared__ fl4 ldsL[3][64];
    int qt = blockIdx.x, h = blockIdx.y, b = blockIdx.z;
    int tid = threadIdx.x, w = tid >> 6, lane = tid & 63;
    int l15 = lane & 15, quad = lane >> 4;
    int bh = b * NH + h;
    int q0 = qt * 64 + l15;
    const unsigned short* qb = Qt + (size_t)bh * P_TOT * HD + quad * 4;
    sh4 qf0 = *(const sh4*)(qb + (size_t)q0 * HD);
    sh4 qf1 = *(const sh4*)(qb + (size_t)(q0 + 16) * HD);
    sh4 qf2 = *(const sh4*)(qb + (size_t)(q0 + 32) * HD);
    sh4 qf3 = *(const sh4*)(qb + (size_t)(q0 + 48) * HD);
    int ko = w * (P_TOT / 4);
    const unsigned short* kb = Kt + (size_t)bh * P_TOT * HD + quad * 4;
    const unsigned short* vb = Vn + ((size_t)bh * HD + l15) * P_TOT + quad * 4;
    fl4 zero = {0.f, 0.f, 0.f, 0.f};
    fl4 o0 = zero, o1 = zero, o2 = zero, o3 = zero;
    fl4 ls = zero;
    for (int kp = ko; kp < ko + P_TOT / 4; kp += 16) {
        sh4 kf = *(const sh4*)(kb + (size_t)(kp + l15) * HD);
        sh4 vf = *(const sh4*)(vb + kp);
        fl4 s0 = __builtin_amdgcn_mfma_f32_16x16x16bf16_1k(kf, qf0, zero, 0, 0, 0);
        fl4 s1 = __builtin_amdgcn_mfma_f32_16x16x16bf16_1k(kf, qf1, zero, 0, 0, 0);
        fl4 s2 = __builtin_amdgcn_mfma_f32_16x16x16bf16_1k(kf, qf2, zero, 0, 0, 0);
        fl4 s3 = __builtin_amdgcn_mfma_f32_16x16x16bf16_1k(kf, qf3, zero, 0, 0, 0);
        float e00 = __builtin_amdgcn_exp2f(s0[0]), e01 = __builtin_amdgcn_exp2f(s0[1]);
        float e02 = __builtin_amdgcn_exp2f(s0[2]), e03 = __builtin_amdgcn_exp2f(s0[3]);
        float e10 = __builtin_amdgcn_exp2f(s1[0]), e11 = __builtin_amdgcn_exp2f(s1[1]);
        float e12 = __builtin_amdgcn_exp2f(s1[2]), e13 = __builtin_amdgcn_exp2f(s1[3]);
        float e20 = __builtin_amdgcn_exp2f(s2[0]), e21 = __builtin_amdgcn_exp2f(s2[1]);
        float e22 = __builtin_amdgcn_exp2f(s2[2]), e23 = __builtin_amdgcn_exp2f(s2[3]);
        float e30 = __builtin_amdgcn_exp2f(s3[0]), e31 = __builtin_amdgcn_exp2f(s3[1]);
        float e32 = __builtin_amdgcn_exp2f(s3[2]), e33 = __builtin_amdgcn_exp2f(s3[3]);
        ls[0] += (e00 + e01) + (e02 + e03);
        ls[1] += (e10 + e11) + (e12 + e13);
        ls[2] += (e20 + e21) + (e22 + e23);
        ls[3] += (e30 + e31) + (e32 + e33);
        sh4 pf0, pf1, pf2, pf3;
        ((unsigned*)&pf0)[0] = pack_bf2_trunc(e00, e01);
        ((unsigned*)&pf0)[1] = pack_bf2_trunc(e02, e03);
        ((unsigned*)&pf1)[0] = pack_bf2_trunc(e10, e11);
        ((unsigned*)&pf1)[1] = pack_bf2_trunc(e12, e13);
        ((unsigned*)&pf2)[0] = pack_bf2_trunc(e20, e21);
        ((unsigned*)&pf2)[1] = pack_bf2_trunc(e22, e23);
        ((unsigned*)&pf3)[0] = pack_bf2_trunc(e30, e31);
        ((unsigned*)&pf3)[1] = pack_bf2_trunc(e32, e33);
        o0 = __builtin_amdgcn_mfma_f32_16x16x16bf16_1k(vf, pf0, o0, 0, 0, 0);
        o1 = __builtin_amdgcn_mfma_f32_16x16x16bf16_1k(vf, pf1, o1, 0, 0, 0);
        o2 = __builtin_amdgcn_mfma_f32_16x16x16bf16_1k(vf, pf2, o2, 0, 0, 0);
        o3 = __builtin_amdgcn_mfma_f32_16x16x16bf16_1k(vf, pf3, o3, 0, 0, 0);
    }
    if (w > 0) {
        ldsO[0][w - 1][lane] = o0;
        ldsO[1][w - 1][lane] = o1;
        ldsO[2][w - 1][lane] = o2;
        ldsO[3][w - 1][lane] = o3;
        ldsL[w - 1][lane] = ls;
    }
    __syncthreads();
    if (w > 0) return;
#pragma unroll
    for (int s = 0; s < 3; ++s) {
        o0 += ldsO[0][s][lane];
        o1 += ldsO[1][s][lane];
        o2 += ldsO[2][s][lane];
        o3 += ldsO[3][s][lane];
        ls += ldsL[s][lane];
    }
#pragma unroll
    for (int i = 0; i < 4; ++i) {
        ls[i] += __shfl_xor(ls[i], 16);
        ls[i] += __shfl_xor(ls[i], 32);
    }
    float i0 = 1.f / ls[0], i1 = 1.f / ls[1], i2 = 1.f / ls[2], i3 = 1.f / ls[3];
    unsigned short* ob = Ot + (size_t)bh * P_TOT * HD + quad * 4;
    uint2 v;
    v.x = pack_bf2(o0[0] * i0, o0[1] * i0); v.y = pack_bf2(o0[2] * i0, o0[3] * i0);
    *(uint2*)(ob + (size_t)q0 * HD) = v;
    v.x = pack_bf2(o1[0] * i1, o1[1] * i1); v.y = pack_bf2(o1[2] * i1, o1[3] * i1);
    *(uint2*)(ob + (size_t)(q0 + 16) * HD) = v;
    v.x = pack_bf2(o2[0] * i2, o2[1] * i2); v.y = pack_bf2(o2[2] * i2, o2[3] * i2);
    *(uint2*)(ob + (size_t)(q0 + 32) * HD) = v;
    v.x = pack_bf2(o3[0] * i3, o3[1] * i3); v.y = pack_bf2(o3[2] * i3, o3[3] * i3);
    *(uint2*)(ob + (size_t)(q0 + 48) * HD) = v;
}

// ---------------- Kernel 3: output projection + bias + 3 residuals, f32,
// operand-swapped MFMA so each lane holds 4 consecutive p -> float4 epilogue.
// grid (144 p-tiles of 16, 8 = cz*4+b), 128 thr (2 waves); wave handles 64 ch.
__global__ __launch_bounds__(128) void k_out(
    const unsigned short* __restrict__ Ot, const unsigned short* __restrict__ Wob,
    const float* __restrict__ bo, const float* __restrict__ rgb,
    const float* __restrict__ depth, const float* __restrict__ rgbd,
    float* __restrict__ out) {
    int nt = blockIdx.x, by = blockIdx.y;
    int cz = by >> 2, b = by & 3;
    int tid = threadIdx.x, w = tid >> 6, lane = tid & 63;
    int l15 = lane & 15, quad = lane >> 4;
    int p0 = nt * 16;
    fl4 zero = {0.f, 0.f, 0.f, 0.f};
    fl4 acc[4];
#pragma unroll
    for (int i = 0; i < 4; ++i) acc[i] = zero;
#pragma unroll
    for (int k0 = 0; k0 < INTER; k0 += 32) {
        int h = (k0 >> 4) + (quad >> 1);
        int doff = 8 * (quad & 1);
        sh8 bfr = *(const sh8*)(Ot + ((size_t)(b * NH + h) * P_TOT + p0 + l15) * HD + doff);
#pragma unroll
        for (int mf2 = 0; mf2 < 4; ++mf2) {
            int mf = (cz * 2 + w) * 4 + mf2;
            sh8 af = *(const sh8*)(Wob + (size_t)(mf * 16 + l15) * INTER + k0 + quad * 8);
            // swapped: C col = Wo-row (channel), C row = p offset
            acc[mf2] = __builtin_amdgcn_mfma_f32_16x16x32_bf16(bfr, af, acc[mf2], 0, 0, 0);
        }
    }
    const size_t outsz = (size_t)4 * C_IN * P_TOT;
#pragma unroll
    for (int mf2 = 0; mf2 < 4; ++mf2) {
        int ch = ((cz * 2 + w) * 4 + mf2) * 16 + l15;
        float bb = bo[ch];
        size_t idx = ((size_t)b * C_IN + ch) * P_TOT + p0 + quad * 4;
        float r0 = acc[mf2][0] + bb, r1 = acc[mf2][1] + bb;
        float r2 = acc[mf2][2] + bb, r3 = acc[mf2][3] + bb;
        float4 a = *(const float4*)(rgb + idx);
        float4 d = *(const float4*)(depth + idx);
        float4 g = *(const float4*)(rgbd + idx);
        float4 o;
        o.x = a.x + r0; o.y = a.y + r1; o.z = a.z + r2; o.w = a.w + r3;
        *(float4*)(out + idx) = o;
        o.x = d.x + r0; o.y = d.y + r1; o.z = d.z + r2; o.w = d.w + r3;
        *(float4*)(out + outsz + idx) = o;
        o.x = g.x + r0; o.y = g.y + r1; o.z = g.z + r2; o.w = g.w + r3;
        *(float4*)(out + 2 * outsz + idx) = o;
    }
}

extern "C" void kernel_launch(void* const* d_in, const int* in_sizes, int n_in,
                              void* d_out, int out_size, void* d_ws, size_t ws_size,
                              hipStream_t stream) {
    (void)in_sizes; (void)n_in; (void)out_size; (void)ws_size;
    const float* rgb   = (const float*)d_in[0];
    const float* depth = (const float*)d_in[1];
    const float* rgbd  = (const float*)d_in[2];
    const float* Wq = (const float*)d_in[3];
    const float* bq = (const float*)d_in[4];
    const float* Wk = (const float*)d_in[5];
    const float* bk = (const float*)d_in[6];
    const float* Wv = (const float*)d_in[7];
    const float* bv = (const float*)d_in[8];
    const float* Wo = (const float*)d_in[9];
    const float* bo = (const float*)d_in[10];

    // Qt/Kt/Vn (bf16, 7.08 MB) live in d_out (28.3 MB f32), dead before k_out
    // overwrites it. d_ws: Ot (2.36 MB) + Wb (0.26 MB).
    float* outp = (float*)d_out;
    unsigned short* Qt = (unsigned short*)d_out;
    unsigned short* Kt = Qt + (size_t)4 * P_TOT * INTER;
    unsigned short* Vn = Kt + (size_t)4 * P_TOT * INTER;
    unsigned short* Ot = (unsigned short*)d_ws;
    unsigned short* Wb = Ot + (size_t)4 * P_TOT * INTER;

    k_prep<<<512, 256, 0, stream>>>(Wq, Wk, Wv, Wo, Wb);
    k_qkv<<<dim3(72, 12), 128, 0, stream>>>(rgb, depth, rgbd, Wb, bq, bk, bv, Qt, Kt, Vn);
    k_attn<<<dim3(36, NH, 4), 256, 0, stream>>>(Qt, Kt, Vn, Ot);
    k_out<<<dim3(144, 8), 128, 0, stream>>>(Ot, Wb + 3 * 32768, bo, rgb, depth, rgbd, outp);
}

// Round 7
// 169.998 us; speedup vs baseline: 2.0552x; 1.0207x over previous
//
#include <hip/hip_runtime.h>
#include <stdint.h>

#define P_TOT 2304
#define C_IN  256
#define INTER 128
#define NH    8
#define HD    16
// fold 1/sqrt(16) * log2(e) into Q so attention does exp2(S) directly
#define QSCALE 0.36067376022224087f

typedef short sh4 __attribute__((ext_vector_type(4)));
typedef short sh8 __attribute__((ext_vector_type(8)));
typedef float fl4 __attribute__((ext_vector_type(4)));

static __device__ __forceinline__ unsigned short f2bf(float f) {
    union { float f; unsigned u; } v; v.f = f;
    return (unsigned short)((v.u + 0x7fffu + ((v.u >> 16) & 1u)) >> 16);
}
// pack two floats as bf16 pair, round-half-up (1 perm + 2 adds)
static __device__ __forceinline__ unsigned pack_bf2(float a, float b) {
    union { float f; unsigned u; } x, y; x.f = a; y.f = b;
    return __builtin_amdgcn_perm(y.u + 0x8000u, x.u + 0x8000u, 0x07060302u);
}
// truncating pack (1 perm). Downward bias cancels in softmax normalization.
static __device__ __forceinline__ unsigned pack_bf2_trunc(float a, float b) {
    union { float f; unsigned u; } x, y; x.f = a; y.f = b;
    return __builtin_amdgcn_perm(y.u, x.u, 0x07060302u);
}

// ---------------- Kernel 0: weights f32 -> bf16. Wb: [Wq][Wk][Wv][Wo] 32768 each.
__global__ __launch_bounds__(256) void k_prep(
    const float* __restrict__ Wq, const float* __restrict__ Wk,
    const float* __restrict__ Wv, const float* __restrict__ Wo,
    unsigned short* __restrict__ Wb) {
    int i = blockIdx.x * 256 + threadIdx.x;
    int seg = i >> 15, off = i & 32767;
    const float* s = (seg == 0 ? Wq : (seg == 1 ? Wk : (seg == 2 ? Wv : Wo)));
    Wb[i] = f2bf(s[off]);
}

// ---------------- Kernel 1: QKV projection, LDS-free loads, 2-way C-split.
// grid (72 p-tiles of 32, 12 = pr*4+b), 256 thr = 4 waves: wave w -> p-sub (w&1),
// c-half (w>>1); partial accs combined via LDS -> 3456 waves (2x occupancy).
// Q (pre-scaled), K head-major [b][h][p][16]; V [b][h][d][P] via swapped MFMA.
__global__ __launch_bounds__(256) void k_qkv(
    const float* __restrict__ rgb, const float* __restrict__ depth,
    const float* __restrict__ rgbd, const unsigned short* __restrict__ Wb,
    const float* __restrict__ bq, const float* __restrict__ bk,
    const float* __restrict__ bv,
    unsigned short* __restrict__ Qt, unsigned short* __restrict__ Kt,
    unsigned short* __restrict__ Vn) {
    __shared__ fl4 ldsA[2][8][64]; // [p-sub][mf][lane] partials from c-half 1
    int nt = blockIdx.x, pb = blockIdx.y;
    int pr = pb >> 2, b = pb & 3;
    const unsigned short* W = Wb + pr * (INTER * C_IN);
    const float* bias = (pr == 0 ? bq : (pr == 1 ? bk : bv));
    const float* X = (pr == 0 ? rgb : (pr == 1 ? depth : rgbd)) + (size_t)b * C_IN * P_TOT;
    int tid = threadIdx.x, w = tid >> 6, lane = tid & 63;
    int wp = w & 1, chalf = w >> 1;
    int l15 = lane & 15, quad = lane >> 4;
    int p = nt * 32 + wp * 16 + l15;
    fl4 zero = {0.f, 0.f, 0.f, 0.f};
    fl4 acc[8];
#pragma unroll
    for (int i = 0; i < 8; ++i) acc[i] = zero;
    const float* xcol = X + p;
    int kbeg = chalf * 128;
#pragma unroll
    for (int kk = 0; kk < 128; kk += 32) {
        int k0 = kbeg + kk;
        int cb = k0 + quad * 8;
        unsigned u[8];
#pragma unroll
        for (int j = 0; j < 8; ++j) {
            union { float f; unsigned uu; } t;
            t.f = xcol[(size_t)(cb + j) * P_TOT];
            u[j] = t.uu;
        }
        sh8 bfr;
        unsigned* bu = (unsigned*)&bfr;
        bu[0] = __builtin_amdgcn_perm(u[1] + 0x8000u, u[0] + 0x8000u, 0x07060302u);
        bu[1] = __builtin_amdgcn_perm(u[3] + 0x8000u, u[2] + 0x8000u, 0x07060302u);
        bu[2] = __builtin_amdgcn_perm(u[5] + 0x8000u, u[4] + 0x8000u, 0x07060302u);
        bu[3] = __builtin_amdgcn_perm(u[7] + 0x8000u, u[6] + 0x8000u, 0x07060302u);
        if (pr < 2) {
#pragma unroll
            for (int mf = 0; mf < 8; ++mf) {
                sh8 af = *(const sh8*)(W + (size_t)(mf * 16 + l15) * C_IN + k0 + quad * 8);
                acc[mf] = __builtin_amdgcn_mfma_f32_16x16x32_bf16(af, bfr, acc[mf], 0, 0, 0);
            }
        } else {
#pragma unroll
            for (int mf = 0; mf < 8; ++mf) {
                sh8 af = *(const sh8*)(W + (size_t)(mf * 16 + l15) * C_IN + k0 + quad * 8);
                // swapped: C col = W-row (channel), C row = p offset
                acc[mf] = __builtin_amdgcn_mfma_f32_16x16x32_bf16(bfr, af, acc[mf], 0, 0, 0);
            }
        }
    }
    if (chalf == 1) {
#pragma unroll
        for (int mf = 0; mf < 8; ++mf) ldsA[wp][mf][lane] = acc[mf];
    }
    __syncthreads();
    if (chalf == 1) return;
#pragma unroll
    for (int mf = 0; mf < 8; ++mf) acc[mf] += ldsA[wp][mf][lane];
    if (pr < 2) {
        unsigned short* dst0 = (pr == 0 ? Qt : Kt);
        float sc = (pr == 0 ? QSCALE : 1.0f);
#pragma unroll
        for (int mf = 0; mf < 8; ++mf) {
            float4 bb = *(const float4*)(bias + mf * 16 + quad * 4);
            uint2 v;
            v.x = pack_bf2((acc[mf][0] + bb.x) * sc, (acc[mf][1] + bb.y) * sc);
            v.y = pack_bf2((acc[mf][2] + bb.z) * sc, (acc[mf][3] + bb.w) * sc);
            *(uint2*)(dst0 + ((size_t)(b * NH + mf) * P_TOT + p) * HD + quad * 4) = v;
        }
    } else {
        int pv = nt * 32 + wp * 16 + quad * 4;
#pragma unroll
        for (int mf = 0; mf < 8; ++mf) {
            float bb = bias[mf * 16 + l15];
            uint2 v;
            v.x = pack_bf2(acc[mf][0] + bb, acc[mf][1] + bb);
            v.y = pack_bf2(acc[mf][2] + bb, acc[mf][3] + bb);
            *(uint2*)(Vn + ((size_t)(b * NH + mf) * HD + l15) * P_TOT + pv) = v;
        }
    }
}

// ---------------- Kernel 2: attention, no-max softmax (scores bounded ~|3|),
// raw v_exp_f32, software-pipelined K/V loads (prefetch iter+1 before compute).
// grid (36 q-tiles of 64, 8 h, 4 b) = 1152 blocks, 256 thr = 4 waves; each wave:
// same 64 q (4 streams), its own quarter of keys; partials combined via LDS.
__global__ __launch_bounds__(256) void k_attn(
    const unsigned short* __restrict__ Qt, const unsigned short* __restrict__ Kt,
    const unsigned short* __restrict__ Vn, unsigned short* __restrict__ Ot) {
    __shared__ fl4 ldsO[4][3][64];
    __shared__ fl4 ldsL[3][64];
    int qt = blockIdx.x, h = blockIdx.y, b = blockIdx.z;
    int tid = threadIdx.x, w = tid >> 6, lane = tid & 63;
    int l15 = lane & 15, quad = lane >> 4;
    int bh = b * NH + h;
    int q0 = qt * 64 + l15;
    const unsigned short* qb = Qt + (size_t)bh * P_TOT * HD + quad * 4;
    sh4 qf0 = *(const sh4*)(qb + (size_t)q0 * HD);
    sh4 qf1 = *(const sh4*)(qb + (size_t)(q0 + 16) * HD);
    sh4 qf2 = *(const sh4*)(qb + (size_t)(q0 + 32) * HD);
    sh4 qf3 = *(const sh4*)(qb + (size_t)(q0 + 48) * HD);
    int ko = w * (P_TOT / 4);
    const unsigned short* kb = Kt + (size_t)bh * P_TOT * HD + (size_t)(ko + l15) * HD + quad * 4;
    const unsigned short* vb = Vn + ((size_t)bh * HD + l15) * P_TOT + quad * 4 + ko;
    fl4 zero = {0.f, 0.f, 0.f, 0.f};
    fl4 o0 = zero, o1 = zero, o2 = zero, o3 = zero;
    fl4 ls = zero;
    const int NIT = P_TOT / 4 / 16; // 36
    sh4 kf = *(const sh4*)kb;
    sh4 vf = *(const sh4*)vb;
    for (int it = 0; it < NIT; ++it) {
        int nx = (it + 1 < NIT) ? it + 1 : it;
        sh4 kf_n = *(const sh4*)(kb + (size_t)nx * 16 * HD);
        sh4 vf_n = *(const sh4*)(vb + nx * 16);
        fl4 s0 = __builtin_amdgcn_mfma_f32_16x16x16bf16_1k(kf, qf0, zero, 0, 0, 0);
        fl4 s1 = __builtin_amdgcn_mfma_f32_16x16x16bf16_1k(kf, qf1, zero, 0, 0, 0);
        fl4 s2 = __builtin_amdgcn_mfma_f32_16x16x16bf16_1k(kf, qf2, zero, 0, 0, 0);
        fl4 s3 = __builtin_amdgcn_mfma_f32_16x16x16bf16_1k(kf, qf3, zero, 0, 0, 0);
        float e00 = __builtin_amdgcn_exp2f(s0[0]), e01 = __builtin_amdgcn_exp2f(s0[1]);
        float e02 = __builtin_amdgcn_exp2f(s0[2]), e03 = __builtin_amdgcn_exp2f(s0[3]);
        float e10 = __builtin_amdgcn_exp2f(s1[0]), e11 = __builtin_amdgcn_exp2f(s1[1]);
        float e12 = __builtin_amdgcn_exp2f(s1[2]), e13 = __builtin_amdgcn_exp2f(s1[3]);
        float e20 = __builtin_amdgcn_exp2f(s2[0]), e21 = __builtin_amdgcn_exp2f(s2[1]);
        float e22 = __builtin_amdgcn_exp2f(s2[2]), e23 = __builtin_amdgcn_exp2f(s2[3]);
        float e30 = __builtin_amdgcn_exp2f(s3[0]), e31 = __builtin_amdgcn_exp2f(s3[1]);
        float e32 = __builtin_amdgcn_exp2f(s3[2]), e33 = __builtin_amdgcn_exp2f(s3[3]);
        ls[0] += (e00 + e01) + (e02 + e03);
        ls[1] += (e10 + e11) + (e12 + e13);
        ls[2] += (e20 + e21) + (e22 + e23);
        ls[3] += (e30 + e31) + (e32 + e33);
        sh4 pf0, pf1, pf2, pf3;
        ((unsigned*)&pf0)[0] = pack_bf2_trunc(e00, e01);
        ((unsigned*)&pf0)[1] = pack_bf2_trunc(e02, e03);
        ((unsigned*)&pf1)[0] = pack_bf2_trunc(e10, e11);
        ((unsigned*)&pf1)[1] = pack_bf2_trunc(e12, e13);
        ((unsigned*)&pf2)[0] = pack_bf2_trunc(e20, e21);
        ((unsigned*)&pf2)[1] = pack_bf2_trunc(e22, e23);
        ((unsigned*)&pf3)[0] = pack_bf2_trunc(e30, e31);
        ((unsigned*)&pf3)[1] = pack_bf2_trunc(e32, e33);
        o0 = __builtin_amdgcn_mfma_f32_16x16x16bf16_1k(vf, pf0, o0, 0, 0, 0);
        o1 = __builtin_amdgcn_mfma_f32_16x16x16bf16_1k(vf, pf1, o1, 0, 0, 0);
        o2 = __builtin_amdgcn_mfma_f32_16x16x16bf16_1k(vf, pf2, o2, 0, 0, 0);
        o3 = __builtin_amdgcn_mfma_f32_16x16x16bf16_1k(vf, pf3, o3, 0, 0, 0);
        kf = kf_n;
        vf = vf_n;
    }
    if (w > 0) {
        ldsO[0][w - 1][lane] = o0;
        ldsO[1][w - 1][lane] = o1;
        ldsO[2][w - 1][lane] = o2;
        ldsO[3][w - 1][lane] = o3;
        ldsL[w - 1][lane] = ls;
    }
    __syncthreads();
    if (w > 0) return;
#pragma unroll
    for (int s = 0; s < 3; ++s) {
        o0 += ldsO[0][s][lane];
        o1 += ldsO[1][s][lane];
        o2 += ldsO[2][s][lane];
        o3 += ldsO[3][s][lane];
        ls += ldsL[s][lane];
    }
#pragma unroll
    for (int i = 0; i < 4; ++i) {
        ls[i] += __shfl_xor(ls[i], 16);
        ls[i] += __shfl_xor(ls[i], 32);
    }
    float i0 = 1.f / ls[0], i1 = 1.f / ls[1], i2 = 1.f / ls[2], i3 = 1.f / ls[3];
    unsigned short* ob = Ot + (size_t)bh * P_TOT * HD + quad * 4;
    uint2 v;
    v.x = pack_bf2(o0[0] * i0, o0[1] * i0); v.y = pack_bf2(o0[2] * i0, o0[3] * i0);
    *(uint2*)(ob + (size_t)q0 * HD) = v;
    v.x = pack_bf2(o1[0] * i1, o1[1] * i1); v.y = pack_bf2(o1[2] * i1, o1[3] * i1);
    *(uint2*)(ob + (size_t)(q0 + 16) * HD) = v;
    v.x = pack_bf2(o2[0] * i2, o2[1] * i2); v.y = pack_bf2(o2[2] * i2, o2[3] * i2);
    *(uint2*)(ob + (size_t)(q0 + 32) * HD) = v;
    v.x = pack_bf2(o3[0] * i3, o3[1] * i3); v.y = pack_bf2(o3[2] * i3, o3[3] * i3);
    *(uint2*)(ob + (size_t)(q0 + 48) * HD) = v;
}

// ---------------- Kernel 3: output projection + bias + 3 residuals, f32,
// swapped MFMA (lane holds 4 consecutive p). One mf (16 ch) per wave ->
// grid (144 p-tiles of 16, 4 mf-groups, 4 b) x 4 waves = 9216 waves (9/SIMD).
__global__ __launch_bounds__(256) void k_out(
    const unsigned short* __restrict__ Ot, const unsigned short* __restrict__ Wob,
    const float* __restrict__ bo, const float* __restrict__ rgb,
    const float* __restrict__ depth, const float* __restrict__ rgbd,
    float* __restrict__ out) {
    int nt = blockIdx.x, mg = blockIdx.y, b = blockIdx.z;
    int tid = threadIdx.x, w = tid >> 6, lane = tid & 63;
    int l15 = lane & 15, quad = lane >> 4;
    int mf = mg * 4 + w;
    int p0 = nt * 16;
    fl4 zero = {0.f, 0.f, 0.f, 0.f};
    fl4 acc = zero;
#pragma unroll
    for (int k0 = 0; k0 < INTER; k0 += 32) {
        int h = (k0 >> 4) + (quad >> 1);
        int doff = 8 * (quad & 1);
        sh8 bfr = *(const sh8*)(Ot + ((size_t)(b * NH + h) * P_TOT + p0 + l15) * HD + doff);
        sh8 af = *(const sh8*)(Wob + (size_t)(mf * 16 + l15) * INTER + k0 + quad * 8);
        // swapped: C col = Wo-row (channel), C row = p offset
        acc = __builtin_amdgcn_mfma_f32_16x16x32_bf16(bfr, af, acc, 0, 0, 0);
    }
    const size_t outsz = (size_t)4 * C_IN * P_TOT;
    int ch = mf * 16 + l15;
    float bb = bo[ch];
    size_t idx = ((size_t)b * C_IN + ch) * P_TOT + p0 + quad * 4;
    float r0 = acc[0] + bb, r1 = acc[1] + bb, r2 = acc[2] + bb, r3 = acc[3] + bb;
    float4 a = *(const float4*)(rgb + idx);
    float4 d = *(const float4*)(depth + idx);
    float4 g = *(const float4*)(rgbd + idx);
    float4 o;
    o.x = a.x + r0; o.y = a.y + r1; o.z = a.z + r2; o.w = a.w + r3;
    *(float4*)(out + idx) = o;
    o.x = d.x + r0; o.y = d.y + r1; o.z = d.z + r2; o.w = d.w + r3;
    *(float4*)(out + outsz + idx) = o;
    o.x = g.x + r0; o.y = g.y + r1; o.z = g.z + r2; o.w = g.w + r3;
    *(float4*)(out + 2 * outsz + idx) = o;
}

extern "C" void kernel_launch(void* const* d_in, const int* in_sizes, int n_in,
                              void* d_out, int out_size, void* d_ws, size_t ws_size,
                              hipStream_t stream) {
    (void)in_sizes; (void)n_in; (void)out_size; (void)ws_size;
    const float* rgb   = (const float*)d_in[0];
    const float* depth = (const float*)d_in[1];
    const float* rgbd  = (const float*)d_in[2];
    const float* Wq = (const float*)d_in[3];
    const float* bq = (const float*)d_in[4];
    const float* Wk = (const float*)d_in[5];
    const float* bk = (const float*)d_in[6];
    const float* Wv = (const float*)d_in[7];
    const float* bv = (const float*)d_in[8];
    const float* Wo = (const float*)d_in[9];
    const float* bo = (const float*)d_in[10];

    // Qt/Kt/Vn (bf16, 7.08 MB) live in d_out (28.3 MB f32), dead before k_out
    // overwrites it. d_ws: Ot (2.36 MB) + Wb (0.26 MB).
    float* outp = (float*)d_out;
    unsigned short* Qt = (unsigned short*)d_out;
    unsigned short* Kt = Qt + (size_t)4 * P_TOT * INTER;
    unsigned short* Vn = Kt + (size_t)4 * P_TOT * INTER;
    unsigned short* Ot = (unsigned short*)d_ws;
    unsigned short* Wb = Ot + (size_t)4 * P_TOT * INTER;

    k_prep<<<512, 256, 0, stream>>>(Wq, Wk, Wv, Wo, Wb);
    k_qkv<<<dim3(72, 12), 256, 0, stream>>>(rgb, depth, rgbd, Wb, bq, bk, bv, Qt, Kt, Vn);
    k_attn<<<dim3(36, NH, 4), 256, 0, stream>>>(Qt, Kt, Vn, Ot);
    k_out<<<dim3(144, 4, 4), 256, 0, stream>>>(Ot, Wb + 3 * 32768, bo, rgb, depth, rgbd, outp);
}

// Round 8
// 154.417 us; speedup vs baseline: 2.2626x; 1.1009x over previous
//
#include <hip/hip_runtime.h>
#include <stdint.h>

#define P_TOT 2304
#define C_IN  256
#define INTER 128
#define NH    8
#define HD    16
#define NKB   144   // P_TOT/16 key/query tiles
// fold 1/sqrt(16) * log2(e) into Q so attention does exp2(S) directly
#define QSCALE 0.36067376022224087f

typedef short sh4 __attribute__((ext_vector_type(4)));
typedef short sh8 __attribute__((ext_vector_type(8)));
typedef float fl4 __attribute__((ext_vector_type(4)));

static __device__ __forceinline__ unsigned short f2bf(float f) {
    union { float f; unsigned u; } v; v.f = f;
    return (unsigned short)((v.u + 0x7fffu + ((v.u >> 16) & 1u)) >> 16);
}
// pack two floats as bf16 pair, round-half-up (1 perm + 2 adds)
static __device__ __forceinline__ unsigned pack_bf2(float a, float b) {
    union { float f; unsigned u; } x, y; x.f = a; y.f = b;
    return __builtin_amdgcn_perm(y.u + 0x8000u, x.u + 0x8000u, 0x07060302u);
}
// truncating pack (1 perm). Downward bias cancels in softmax normalization.
static __device__ __forceinline__ unsigned pack_bf2_trunc(float a, float b) {
    union { float f; unsigned u; } x, y; x.f = a; y.f = b;
    return __builtin_amdgcn_perm(y.u, x.u, 0x07060302u);
}

// ---------------- Kernel 0: weights f32 -> bf16. Wb: [Wq][Wk][Wv][Wo] 32768 each.
__global__ __launch_bounds__(256) void k_prep(
    const float* __restrict__ Wq, const float* __restrict__ Wk,
    const float* __restrict__ Wv, const float* __restrict__ Wo,
    unsigned short* __restrict__ Wb) {
    int i = blockIdx.x * 256 + threadIdx.x;
    int seg = i >> 15, off = i & 32767;
    const float* s = (seg == 0 ? Wq : (seg == 1 ? Wk : (seg == 2 ? Wv : Wo)));
    Wb[i] = f2bf(s[off]);
}

// ---------------- Kernel 1: QKV projection, LDS-free loads, 2-way C-split.
// grid (72 p-tiles of 32, 12 = pr*4+b), 256 thr = 4 waves.
// Q/K/V written in MFMA-FRAGMENT-TILED layout: tensor[bh][tile(144)][256 halfs],
// lane (l15,quad) offset (quad*16+l15)*4 -> wave-contiguous 512B loads AND stores.
//   Q/K tile element (quad,l15,j) = X[p=tile*16+l15][d=quad*4+j]   (B/A frag of QK)
//   V   tile element (quad,l15,j) = V[d=l15][kpos=quad*4+j]        (A frag of PV)
__global__ __launch_bounds__(256) void k_qkv(
    const float* __restrict__ rgb, const float* __restrict__ depth,
    const float* __restrict__ rgbd, const unsigned short* __restrict__ Wb,
    const float* __restrict__ bq, const float* __restrict__ bk,
    const float* __restrict__ bv,
    unsigned short* __restrict__ Qt, unsigned short* __restrict__ Kt,
    unsigned short* __restrict__ Vn) {
    __shared__ fl4 ldsA[2][8][64]; // [p-sub][mf][lane] partials from c-half 1
    int nt = blockIdx.x, pb = blockIdx.y;
    int pr = pb >> 2, b = pb & 3;
    const unsigned short* W = Wb + pr * (INTER * C_IN);
    const float* bias = (pr == 0 ? bq : (pr == 1 ? bk : bv));
    const float* X = (pr == 0 ? rgb : (pr == 1 ? depth : rgbd)) + (size_t)b * C_IN * P_TOT;
    int tid = threadIdx.x, w = tid >> 6, lane = tid & 63;
    int wp = w & 1, chalf = w >> 1;
    int l15 = lane & 15, quad = lane >> 4;
    int p = nt * 32 + wp * 16 + l15;
    fl4 zero = {0.f, 0.f, 0.f, 0.f};
    fl4 acc[8];
#pragma unroll
    for (int i = 0; i < 8; ++i) acc[i] = zero;
    const float* xcol = X + p;
    int kbeg = chalf * 128;
#pragma unroll
    for (int kk = 0; kk < 128; kk += 32) {
        int k0 = kbeg + kk;
        int cb = k0 + quad * 8;
        unsigned u[8];
#pragma unroll
        for (int j = 0; j < 8; ++j) {
            union { float f; unsigned uu; } t;
            t.f = xcol[(size_t)(cb + j) * P_TOT];
            u[j] = t.uu;
        }
        sh8 bfr;
        unsigned* bu = (unsigned*)&bfr;
        bu[0] = __builtin_amdgcn_perm(u[1] + 0x8000u, u[0] + 0x8000u, 0x07060302u);
        bu[1] = __builtin_amdgcn_perm(u[3] + 0x8000u, u[2] + 0x8000u, 0x07060302u);
        bu[2] = __builtin_amdgcn_perm(u[5] + 0x8000u, u[4] + 0x8000u, 0x07060302u);
        bu[3] = __builtin_amdgcn_perm(u[7] + 0x8000u, u[6] + 0x8000u, 0x07060302u);
        if (pr < 2) {
#pragma unroll
            for (int mf = 0; mf < 8; ++mf) {
                sh8 af = *(const sh8*)(W + (size_t)(mf * 16 + l15) * C_IN + k0 + quad * 8);
                acc[mf] = __builtin_amdgcn_mfma_f32_16x16x32_bf16(af, bfr, acc[mf], 0, 0, 0);
            }
        } else {
#pragma unroll
            for (int mf = 0; mf < 8; ++mf) {
                sh8 af = *(const sh8*)(W + (size_t)(mf * 16 + l15) * C_IN + k0 + quad * 8);
                // swapped: C col = W-row (channel), C row = p offset
                acc[mf] = __builtin_amdgcn_mfma_f32_16x16x32_bf16(bfr, af, acc[mf], 0, 0, 0);
            }
        }
    }
    if (chalf == 1) {
#pragma unroll
        for (int mf = 0; mf < 8; ++mf) ldsA[wp][mf][lane] = acc[mf];
    }
    __syncthreads();
    if (chalf == 1) return;
#pragma unroll
    for (int mf = 0; mf < 8; ++mf) acc[mf] += ldsA[wp][mf][lane];
    int tile = nt * 2 + wp;          // p >> 4
    int loff = (quad * 16 + l15) * 4;
    if (pr < 2) {
        unsigned short* dst0 = (pr == 0 ? Qt : Kt);
        float sc = (pr == 0 ? QSCALE : 1.0f);
#pragma unroll
        for (int mf = 0; mf < 8; ++mf) {
            float4 bb = *(const float4*)(bias + mf * 16 + quad * 4);
            uint2 v;
            v.x = pack_bf2((acc[mf][0] + bb.x) * sc, (acc[mf][1] + bb.y) * sc);
            v.y = pack_bf2((acc[mf][2] + bb.z) * sc, (acc[mf][3] + bb.w) * sc);
            *(uint2*)(dst0 + (size_t)((b * NH + mf) * NKB + tile) * 256 + loff) = v;
        }
    } else {
#pragma unroll
        for (int mf = 0; mf < 8; ++mf) {
            float bb = bias[mf * 16 + l15];
            uint2 v;
            v.x = pack_bf2(acc[mf][0] + bb, acc[mf][1] + bb);
            v.y = pack_bf2(acc[mf][2] + bb, acc[mf][3] + bb);
            *(uint2*)(Vn + (size_t)((b * NH + mf) * NKB + tile) * 256 + loff) = v;
        }
    }
}

// ---------------- Kernel 2: attention, no-max softmax (scores bounded ~|3|),
// raw v_exp_f32, fragment-tiled coalesced loads (512B/wave per dwordx2).
// grid (36 q-tiles of 64, 8 h, 4 b), 512 thr = 8 waves; each wave: same 64 q
// (4 streams), its own 1/8 of the 2304 keys (18 tiles); partials tree-combined
// via LDS (exact: fixed shift 0 => plain sums).
__global__ __launch_bounds__(512) void k_attn(
    const unsigned short* __restrict__ Qt, const unsigned short* __restrict__ Kt,
    const unsigned short* __restrict__ Vn, unsigned short* __restrict__ Ot) {
    __shared__ fl4 red[4][5][64];
    int qt = blockIdx.x, h = blockIdx.y, b = blockIdx.z;
    int tid = threadIdx.x, w = tid >> 6, lane = tid & 63;
    int l15 = lane & 15, quad = lane >> 4;
    int bh = b * NH + h;
    int loff = (quad * 16 + l15) * 4;
    const unsigned short* qb = Qt + (size_t)(bh * NKB + qt * 4) * 256 + loff;
    sh4 qf0 = *(const sh4*)(qb);
    sh4 qf1 = *(const sh4*)(qb + 256);
    sh4 qf2 = *(const sh4*)(qb + 512);
    sh4 qf3 = *(const sh4*)(qb + 768);
    const int NIT = NKB / 8; // 18 tiles per wave
    const unsigned short* kb = Kt + (size_t)(bh * NKB + w * NIT) * 256 + loff;
    const unsigned short* vb = Vn + (size_t)(bh * NKB + w * NIT) * 256 + loff;
    fl4 zero = {0.f, 0.f, 0.f, 0.f};
    fl4 o0 = zero, o1 = zero, o2 = zero, o3 = zero;
    fl4 ls = zero;
    sh4 kf = *(const sh4*)kb;
    sh4 vf = *(const sh4*)vb;
    for (int it = 0; it < NIT; ++it) {
        int nx = (it + 1 < NIT) ? it + 1 : it;
        sh4 kf_n = *(const sh4*)(kb + (size_t)nx * 256);
        sh4 vf_n = *(const sh4*)(vb + (size_t)nx * 256);
        fl4 s0 = __builtin_amdgcn_mfma_f32_16x16x16bf16_1k(kf, qf0, zero, 0, 0, 0);
        fl4 s1 = __builtin_amdgcn_mfma_f32_16x16x16bf16_1k(kf, qf1, zero, 0, 0, 0);
        fl4 s2 = __builtin_amdgcn_mfma_f32_16x16x16bf16_1k(kf, qf2, zero, 0, 0, 0);
        fl4 s3 = __builtin_amdgcn_mfma_f32_16x16x16bf16_1k(kf, qf3, zero, 0, 0, 0);
        float e00 = __builtin_amdgcn_exp2f(s0[0]), e01 = __builtin_amdgcn_exp2f(s0[1]);
        float e02 = __builtin_amdgcn_exp2f(s0[2]), e03 = __builtin_amdgcn_exp2f(s0[3]);
        float e10 = __builtin_amdgcn_exp2f(s1[0]), e11 = __builtin_amdgcn_exp2f(s1[1]);
        float e12 = __builtin_amdgcn_exp2f(s1[2]), e13 = __builtin_amdgcn_exp2f(s1[3]);
        float e20 = __builtin_amdgcn_exp2f(s2[0]), e21 = __builtin_amdgcn_exp2f(s2[1]);
        float e22 = __builtin_amdgcn_exp2f(s2[2]), e23 = __builtin_amdgcn_exp2f(s2[3]);
        float e30 = __builtin_amdgcn_exp2f(s3[0]), e31 = __builtin_amdgcn_exp2f(s3[1]);
        float e32 = __builtin_amdgcn_exp2f(s3[2]), e33 = __builtin_amdgcn_exp2f(s3[3]);
        ls[0] += (e00 + e01) + (e02 + e03);
        ls[1] += (e10 + e11) + (e12 + e13);
        ls[2] += (e20 + e21) + (e22 + e23);
        ls[3] += (e30 + e31) + (e32 + e33);
        sh4 pf0, pf1, pf2, pf3;
        ((unsigned*)&pf0)[0] = pack_bf2_trunc(e00, e01);
        ((unsigned*)&pf0)[1] = pack_bf2_trunc(e02, e03);
        ((unsigned*)&pf1)[0] = pack_bf2_trunc(e10, e11);
        ((unsigned*)&pf1)[1] = pack_bf2_trunc(e12, e13);
        ((unsigned*)&pf2)[0] = pack_bf2_trunc(e20, e21);
        ((unsigned*)&pf2)[1] = pack_bf2_trunc(e22, e23);
        ((unsigned*)&pf3)[0] = pack_bf2_trunc(e30, e31);
        ((unsigned*)&pf3)[1] = pack_bf2_trunc(e32, e33);
        o0 = __builtin_amdgcn_mfma_f32_16x16x16bf16_1k(vf, pf0, o0, 0, 0, 0);
        o1 = __builtin_amdgcn_mfma_f32_16x16x16bf16_1k(vf, pf1, o1, 0, 0, 0);
        o2 = __builtin_amdgcn_mfma_f32_16x16x16bf16_1k(vf, pf2, o2, 0, 0, 0);
        o3 = __builtin_amdgcn_mfma_f32_16x16x16bf16_1k(vf, pf3, o3, 0, 0, 0);
        kf = kf_n;
        vf = vf_n;
    }
    // tree combine across 8 waves (3 rounds)
#pragma unroll
    for (int step = 4; step >= 1; step >>= 1) {
        if (w >= step && w < 2 * step) {
            red[w - step][0][lane] = o0;
            red[w - step][1][lane] = o1;
            red[w - step][2][lane] = o2;
            red[w - step][3][lane] = o3;
            red[w - step][4][lane] = ls;
        }
        __syncthreads();
        if (w < step) {
            o0 += red[w][0][lane];
            o1 += red[w][1][lane];
            o2 += red[w][2][lane];
            o3 += red[w][3][lane];
            ls += red[w][4][lane];
        }
        __syncthreads();
    }
    if (w != 0) return;
#pragma unroll
    for (int i = 0; i < 4; ++i) {
        ls[i] += __shfl_xor(ls[i], 16);
        ls[i] += __shfl_xor(ls[i], 32);
    }
    float i0 = 1.f / ls[0], i1 = 1.f / ls[1], i2 = 1.f / ls[2], i3 = 1.f / ls[3];
    int q0 = qt * 64 + l15;
    unsigned short* ob = Ot + (size_t)bh * P_TOT * HD + quad * 4;
    uint2 v;
    v.x = pack_bf2(o0[0] * i0, o0[1] * i0); v.y = pack_bf2(o0[2] * i0, o0[3] * i0);
    *(uint2*)(ob + (size_t)q0 * HD) = v;
    v.x = pack_bf2(o1[0] * i1, o1[1] * i1); v.y = pack_bf2(o1[2] * i1, o1[3] * i1);
    *(uint2*)(ob + (size_t)(q0 + 16) * HD) = v;
    v.x = pack_bf2(o2[0] * i2, o2[1] * i2); v.y = pack_bf2(o2[2] * i2, o2[3] * i2);
    *(uint2*)(ob + (size_t)(q0 + 32) * HD) = v;
    v.x = pack_bf2(o3[0] * i3, o3[1] * i3); v.y = pack_bf2(o3[2] * i3, o3[3] * i3);
    *(uint2*)(ob + (size_t)(q0 + 48) * HD) = v;
}

// ---------------- Kernel 3: output projection + bias + 3 residuals, f32,
// swapped MFMA (lane holds 4 consecutive p). One mf (16 ch) per wave ->
// grid (144 p-tiles of 16, 4 mf-groups, 4 b) x 4 waves = 9216 waves (9/SIMD).
__global__ __launch_bounds__(256) void k_out(
    const unsigned short* __restrict__ Ot, const unsigned short* __restrict__ Wob,
    const float* __restrict__ bo, const float* __restrict__ rgb,
    const float* __restrict__ depth, const float* __restrict__ rgbd,
    float* __restrict__ out) {
    int nt = blockIdx.x, mg = blockIdx.y, b = blockIdx.z;
    int tid = threadIdx.x, w = tid >> 6, lane = tid & 63;
    int l15 = lane & 15, quad = lane >> 4;
    int mf = mg * 4 + w;
    int p0 = nt * 16;
    fl4 zero = {0.f, 0.f, 0.f, 0.f};
    fl4 acc = zero;
#pragma unroll
    for (int k0 = 0; k0 < INTER; k0 += 32) {
        int h = (k0 >> 4) + (quad >> 1);
        int doff = 8 * (quad & 1);
        sh8 bfr = *(const sh8*)(Ot + ((size_t)(b * NH + h) * P_TOT + p0 + l15) * HD + doff);
        sh8 af = *(const sh8*)(Wob + (size_t)(mf * 16 + l15) * INTER + k0 + quad * 8);
        // swapped: C col = Wo-row (channel), C row = p offset
        acc = __builtin_amdgcn_mfma_f32_16x16x32_bf16(bfr, af, acc, 0, 0, 0);
    }
    const size_t outsz = (size_t)4 * C_IN * P_TOT;
    int ch = mf * 16 + l15;
    float bb = bo[ch];
    size_t idx = ((size_t)b * C_IN + ch) * P_TOT + p0 + quad * 4;
    float r0 = acc[0] + bb, r1 = acc[1] + bb, r2 = acc[2] + bb, r3 = acc[3] + bb;
    float4 a = *(const float4*)(rgb + idx);
    float4 d = *(const float4*)(depth + idx);
    float4 g = *(const float4*)(rgbd + idx);
    float4 o;
    o.x = a.x + r0; o.y = a.y + r1; o.z = a.z + r2; o.w = a.w + r3;
    *(float4*)(out + idx) = o;
    o.x = d.x + r0; o.y = d.y + r1; o.z = d.z + r2; o.w = d.w + r3;
    *(float4*)(out + outsz + idx) = o;
    o.x = g.x + r0; o.y = g.y + r1; o.z = g.z + r2; o.w = g.w + r3;
    *(float4*)(out + 2 * outsz + idx) = o;
}

extern "C" void kernel_launch(void* const* d_in, const int* in_sizes, int n_in,
                              void* d_out, int out_size, void* d_ws, size_t ws_size,
                              hipStream_t stream) {
    (void)in_sizes; (void)n_in; (void)out_size; (void)ws_size;
    const float* rgb   = (const float*)d_in[0];
    const float* depth = (const float*)d_in[1];
    const float* rgbd  = (const float*)d_in[2];
    const float* Wq = (const float*)d_in[3];
    const float* bq = (const float*)d_in[4];
    const float* Wk = (const float*)d_in[5];
    const float* bk = (const float*)d_in[6];
    const float* Wv = (const float*)d_in[7];
    const float* bv = (const float*)d_in[8];
    const float* Wo = (const float*)d_in[9];
    const float* bo = (const float*)d_in[10];

    // Qt/Kt/Vn (bf16, 7.08 MB, fragment-tiled) live in d_out (28.3 MB f32),
    // dead before k_out overwrites it. d_ws: Ot (2.36 MB) + Wb (0.26 MB).
    float* outp = (float*)d_out;
    unsigned short* Qt = (unsigned short*)d_out;
    unsigned short* Kt = Qt + (size_t)4 * P_TOT * INTER;
    unsigned short* Vn = Kt + (size_t)4 * P_TOT * INTER;
    unsigned short* Ot = (unsigned short*)d_ws;
    unsigned short* Wb = Ot + (size_t)4 * P_TOT * INTER;

    k_prep<<<512, 256, 0, stream>>>(Wq, Wk, Wv, Wo, Wb);
    k_qkv<<<dim3(72, 12), 256, 0, stream>>>(rgb, depth, rgbd, Wb, bq, bk, bv, Qt, Kt, Vn);
    k_attn<<<dim3(36, NH, 4), 512, 0, stream>>>(Qt, Kt, Vn, Ot);
    k_out<<<dim3(144, 4, 4), 256, 0, stream>>>(Ot, Wb + 3 * 32768, bo, rgb, depth, rgbd, outp);
}